// Round 14
// baseline (319.500 us; speedup 1.0000x reference)
//
#include <hip/hip_runtime.h>
#include <hip/hip_bf16.h>

#define DF 128
#define CAP 32        // fixed CSR slots per node; Poisson(8) max deg ~24 over 100K nodes
#define OVF_CAP 65536 // overflow edge list capacity (expected 0 used)

// flagI: 1 = edge_index stored as int64, 0 = int32
// flagD: 1 = x/W/b/out are bf16, 0 = fp32

typedef __attribute__((ext_vector_type(8))) short shortx8;   // MFMA A/B frag (8 bf16)
typedef __attribute__((ext_vector_type(4))) float floatx4;   // MFMA C/D frag

__device__ __forceinline__ unsigned short f32_to_bf16_rne(float f) {
    unsigned int u = __float_as_uint(f);
    unsigned int r = (u >> 16) & 1u;
    u += 0x7FFFu + r;
    return (unsigned short)(u >> 16);
}
__device__ __forceinline__ float bf16_lo(unsigned int w) { return __uint_as_float(w << 16); }
__device__ __forceinline__ float bf16_hi(unsigned int w) { return __uint_as_float(w & 0xffff0000u); }
__device__ __forceinline__ unsigned int pack_bf16(float x, float y) {
    return ((unsigned int)f32_to_bf16_rne(y) << 16) | (unsigned int)f32_to_bf16_rne(x);
}

// ---------------- dtype detection ----------------
__global__ void detect_flags_kernel(const unsigned int* __restrict__ ew, int enwords,
                                    const unsigned short* __restrict__ xh, int xnh,
                                    int* __restrict__ flagI, int* __restrict__ flagD) {
    __shared__ int eodd_nz;
    __shared__ int xbig;
    if (threadIdx.x == 0) { eodd_nz = 0; xbig = 0; }
    __syncthreads();
    int f1 = 0;
    for (int i = 1 + 2 * (int)threadIdx.x; i < enwords; i += 2 * (int)blockDim.x)
        if (ew[i] != 0u) f1 = 1;
    int c = 0;
    for (int i = 2 * (int)threadIdx.x; i < xnh; i += 2 * (int)blockDim.x) {
        unsigned int e = ((unsigned int)xh[i] >> 7) & 0xFFu;
        if (e >= 0xC0u) c++;   // |v| >= 2^65 viewed as bf16 -> impossible for real data
    }
    if (f1) eodd_nz = 1;
    if (c) atomicAdd(&xbig, c);
    __syncthreads();
    if (threadIdx.x == 0) {
        *flagI = (eodd_nz == 0) ? 1 : 0;
        *flagD = (xbig > 8) ? 0 : 1;
    }
}

// ---------------- PREP: count + direct fixed-stride CSR slot write + casts (fused) ----
// Round-11 evidence: prep = 66us, VALUBusy 2.4% @ 65% occupancy, 20% HBM -> waves
// stall on the 800K device-scope returning atomics. Falsification test this round:
// 8 edges/thread (8 independent atomics in flight, was 4) separates atomic-LATENCY
// (should drop to ~45-50us) from fabric atomic-THROUGHPUT (unchanged). csrF stores
// made non-temporal: no reuse before next kernel; may cut the ~7x cross-XCD dirty-
// line writeback amplification (WRITE_SIZE 72.7MB for ~29MB of payload).
__global__ __launch_bounds__(256) void prep_kernel(
        const int* __restrict__ eidx, const int* __restrict__ flagI,
        const int* __restrict__ flagD, int E, int n,
        int* __restrict__ cnt, int* __restrict__ csrF,
        int2* __restrict__ ovf, int* __restrict__ ovf_cnt,
        const void* __restrict__ x, uint2* __restrict__ xb, int nw2,
        const void* __restrict__ W, const void* __restrict__ b,
        unsigned short* __restrict__ Wb, float* __restrict__ bias_f,
        int g1, int g2) {
    int bid = (int)blockIdx.x;
    if (bid < g1) {
        // ---- count + slot write: 8 edges/thread, 8 independent atomics in flight ----
        int t = bid * 256 + (int)threadIdx.x;
        int base = t * 8;
        if (base >= E) return;
        int isI64 = *flagI;
        const long long* p64 = (const long long*)eidx;
        int s[8], d[8];
#pragma unroll
        for (int j = 0; j < 8; ++j) {
            int e = base + j;
            if (e < E) {
                if (isI64) { s[j] = (int)p64[e]; d[j] = (int)p64[(long long)E + e]; }
                else       { s[j] = eidx[e];     d[j] = eidx[E + e]; }
            } else { s[j] = -1; d[j] = -1; }
        }
        int r[8];
#pragma unroll
        for (int j = 0; j < 8; ++j) {
            bool ok = ((unsigned)d[j] < (unsigned)n) && ((unsigned)s[j] < (unsigned)n);
            r[j] = ok ? atomicAdd(&cnt[d[j]], 1) : -1;
        }
#pragma unroll
        for (int j = 0; j < 8; ++j) {
            if (r[j] < 0) continue;
            if (r[j] < CAP) {
                __builtin_nontemporal_store(s[j], &csrF[d[j] * CAP + r[j]]);
            } else {
                int p = atomicAdd(ovf_cnt, 1);
                if (p < OVF_CAP) ovf[p] = make_int2(s[j], d[j]);
            }
        }
    } else if (bid < g1 + g2) {
        // ---- cast_x: x -> packed bf16 rows (or copy if already bf16) ----
        int i = (bid - g1) * 256 + (int)threadIdx.x;
        if (i >= nw2) return;
        if (*flagD) {
            xb[i] = ((const uint2*)x)[i];
        } else {
            float4 v = ((const float4*)x)[i];
            uint2 o;
            o.x = pack_bf16(v.x, v.y);
            o.y = pack_bf16(v.z, v.w);
            xb[i] = o;
        }
    } else {
        // ---- cast_wb: W -> bf16, b -> fp32 ----
        int i = (bid - g1 - g2) * 256 + (int)threadIdx.x;
        int bf = *flagD;
        if (i < 128 * 128)
            Wb[i] = bf ? ((const unsigned short*)W)[i] : f32_to_bf16_rne(((const float*)W)[i]);
        if (i < 128)
            bias_f[i] = bf ? bf16_lo((unsigned int)((const unsigned short*)b)[i]) : ((const float*)b)[i];
    }
}

// ---------------- hop: one wave per node, quarter-wave uint4 gathers, 2x-MLP ----------------
// Fixed-stride CSR: beg = gw*CAP, length cnt[gw] (<=CAP; rest in overflow list).
// Per-edge weight computed on the fly: w = rsqrt(cnt[s]+1) — cnt is a 400KB
// L2-resident table, broadcast load within each quarter. No dinv array.
// out[i] = di*(di*self + sum_s w_s*h[s]),  di = rsqrt(cnt[i]+1)
__global__ __launch_bounds__(256) void hop_kernel(const uint4* __restrict__ hin,
                                                  uint4* __restrict__ hout,
                                                  const int* __restrict__ csrF,
                                                  const int* __restrict__ cnt, int n) {
    int gw = (int)((blockIdx.x * 256 + threadIdx.x) >> 6);
    int lane = (int)(threadIdx.x & 63);
    if (gw >= n) return;
    int e = lane >> 4, c = lane & 15;
    int cv = cnt[gw];
    float di = rsqrtf((float)(cv + 1));
    int beg = gw * CAP;
    int len = cv < CAP ? cv : CAP;
    int end = beg + len;
    uint4 sv = hin[(size_t)gw * 16 + c];     // self row (broadcast across quarters)
    float a0 = 0.f, a1 = 0.f, a2 = 0.f, a3 = 0.f, a4 = 0.f, a5 = 0.f, a6 = 0.f, a7 = 0.f;
    for (int j = beg + e; j < end; j += 8) {
        int s0 = csrF[j];
        bool has1 = (j + 4) < end;
        int s1 = has1 ? csrF[j + 4] : s0;
        uint4 v0 = hin[(size_t)s0 * 16 + c];          // two independent gathers
        uint4 v1 = hin[(size_t)s1 * 16 + c];          // in flight concurrently
        float w0 = rsqrtf((float)(cnt[s0] + 1));
        float w1 = has1 ? rsqrtf((float)(cnt[s1] + 1)) : 0.f;
        a0 += w0 * bf16_lo(v0.x); a1 += w0 * bf16_hi(v0.x);
        a2 += w0 * bf16_lo(v0.y); a3 += w0 * bf16_hi(v0.y);
        a4 += w0 * bf16_lo(v0.z); a5 += w0 * bf16_hi(v0.z);
        a6 += w0 * bf16_lo(v0.w); a7 += w0 * bf16_hi(v0.w);
        a0 += w1 * bf16_lo(v1.x); a1 += w1 * bf16_hi(v1.x);
        a2 += w1 * bf16_lo(v1.y); a3 += w1 * bf16_hi(v1.y);
        a4 += w1 * bf16_lo(v1.z); a5 += w1 * bf16_hi(v1.z);
        a6 += w1 * bf16_lo(v1.w); a7 += w1 * bf16_hi(v1.w);
    }
    // reduce the 4 quarter-partials for each column set
    a0 += __shfl_xor(a0, 16); a0 += __shfl_xor(a0, 32);
    a1 += __shfl_xor(a1, 16); a1 += __shfl_xor(a1, 32);
    a2 += __shfl_xor(a2, 16); a2 += __shfl_xor(a2, 32);
    a3 += __shfl_xor(a3, 16); a3 += __shfl_xor(a3, 32);
    a4 += __shfl_xor(a4, 16); a4 += __shfl_xor(a4, 32);
    a5 += __shfl_xor(a5, 16); a5 += __shfl_xor(a5, 32);
    a6 += __shfl_xor(a6, 16); a6 += __shfl_xor(a6, 32);
    a7 += __shfl_xor(a7, 16); a7 += __shfl_xor(a7, 32);
    // add self term and final scale
    a0 = di * (a0 + di * bf16_lo(sv.x)); a1 = di * (a1 + di * bf16_hi(sv.x));
    a2 = di * (a2 + di * bf16_lo(sv.y)); a3 = di * (a3 + di * bf16_hi(sv.y));
    a4 = di * (a4 + di * bf16_lo(sv.z)); a5 = di * (a5 + di * bf16_hi(sv.z));
    a6 = di * (a6 + di * bf16_lo(sv.w)); a7 = di * (a7 + di * bf16_hi(sv.w));
    if (e == 0) {
        uint4 o;
        o.x = pack_bf16(a0, a1);
        o.y = pack_bf16(a2, a3);
        o.z = pack_bf16(a4, a5);
        o.w = pack_bf16(a6, a7);
        hout[(size_t)gw * 16 + c] = o;
    }
}

// ---------------- overflow fixup: apply dropped-edge contributions (expected 0) ----
// One block, 64 threads; thread t owns packed-uint column t (2 cols). Sequential
// over overflow edges so repeated dst is handled correctly (loop-carried per thread).
__global__ void fixup_kernel(const unsigned int* __restrict__ hin,
                             unsigned int* __restrict__ hout,
                             const int2* __restrict__ ovf, const int* __restrict__ ovf_cnt,
                             const int* __restrict__ cnt) {
    int m = *ovf_cnt;
    if (m > OVF_CAP) m = OVF_CAP;
    int t = (int)threadIdx.x;
    for (int i = 0; i < m; ++i) {
        int2 sd = ovf[i];
        float w  = rsqrtf((float)(cnt[sd.x] + 1));
        float dd = rsqrtf((float)(cnt[sd.y] + 1));
        unsigned int hv = hin[(size_t)sd.x * 64 + t];
        unsigned int ov = hout[(size_t)sd.y * 64 + t];
        float lo = bf16_lo(ov) + dd * w * bf16_lo(hv);
        float hi = bf16_hi(ov) + dd * w * bf16_hi(hv);
        hout[(size_t)sd.y * 64 + t] = pack_bf16(lo, hi);
    }
}

// ---------------- MFMA linear: out = h @ Wb^T + bias (h,Wb bf16; out per flagD) ----------------
__global__ __launch_bounds__(256, 2) void linear_mfma_kernel(
        const unsigned short* __restrict__ h, const unsigned short* __restrict__ Wb,
        const float* __restrict__ bias_f, void* __restrict__ out,
        const int* __restrict__ flagD, int n) {
    int bf = *flagD;
    int wave = (int)(threadIdx.x >> 6);
    int lane = (int)(threadIdx.x & 63);
    int q = lane >> 4, m16 = lane & 15;

    shortx8 bfrag[8][4];
    float bias[8];
#pragma unroll
    for (int nt = 0; nt < 8; ++nt) {
        int wr = nt * 16 + m16;               // W row = output feature o
#pragma unroll
        for (int t = 0; t < 4; ++t)
            bfrag[nt][t] = *(const shortx8*)&Wb[wr * 128 + t * 32 + q * 8];
        bias[nt] = bias_f[wr];
    }

    int nstrips = (n + 15) / 16;
    int wid = (int)blockIdx.x * 4 + wave;
    int nw = (int)gridDim.x * 4;
    for (int s = wid; s < nstrips; s += nw) {
        int row0 = s * 16;
        int arow = row0 + m16;
        if (arow >= n) arow = n - 1;          // clamp (dup rows; stores guarded)
        shortx8 afrag[4];
#pragma unroll
        for (int t = 0; t < 4; ++t)
            afrag[t] = *(const shortx8*)&h[(size_t)arow * 128 + t * 32 + q * 8];

        floatx4 acc[8];
#pragma unroll
        for (int nt = 0; nt < 8; ++nt) acc[nt] = (floatx4){0.f, 0.f, 0.f, 0.f};
#pragma unroll
        for (int t = 0; t < 4; ++t)
#pragma unroll
            for (int nt = 0; nt < 8; ++nt)
                acc[nt] = __builtin_amdgcn_mfma_f32_16x16x32_bf16(afrag[t], bfrag[nt][t], acc[nt], 0, 0, 0);

#pragma unroll
        for (int nt = 0; nt < 8; ++nt)
#pragma unroll
            for (int r = 0; r < 4; ++r) {
                int row = row0 + q * 4 + r;
                if (row < n) {
                    float v = acc[nt][r] + bias[nt];
                    size_t oi = (size_t)row * 128 + nt * 16 + m16;
                    if (bf) ((unsigned short*)out)[oi] = f32_to_bf16_rne(v);
                    else    ((float*)out)[oi] = v;
                }
            }
    }
}

extern "C" void kernel_launch(void* const* d_in, const int* in_sizes, int n_in,
                              void* d_out, int out_size, void* d_ws, size_t ws_size,
                              hipStream_t stream) {
    const void* x = d_in[0];
    const int* eidx = (const int*)d_in[1];
    const void* W = d_in[2];
    const void* b = d_in[3];

    int n = in_sizes[0] / DF;   // 100000
    int E = in_sizes[1] / 2;    // 800000

    // workspace carve-up (~40 MB; d_out hosts the second bf16 ping buffer,
    // safe because out_size*2B >= 25.6MB even for bf16 output)
    char* ws = (char*)d_ws;
    size_t off = 0;
    auto alloc = [&](size_t bytes) -> void* {
        void* p = ws + off;
        off = (off + bytes + 255) & ~(size_t)255;
        return p;
    };
    unsigned int* hb = (unsigned int*)alloc((size_t)n * 64 * 4);   // bf16 rows, 25.6MB
    int*   cnt       = (int*)alloc((size_t)n * 4);
    int*   flagI     = (int*)alloc(256);
    int*   flagD     = (int*)alloc(256);
    unsigned short* Wb = (unsigned short*)alloc(128 * 128 * 2);    // bf16 W
    float* bias_f    = (float*)alloc(128 * 4);
    int*   csrF      = (int*)alloc((size_t)n * CAP * 4);           // fixed-stride CSR, 12.8MB
    int2*  ovf       = (int2*)alloc((size_t)OVF_CAP * 8);          // overflow edges, 512KB
    int*   ovf_cnt   = (int*)alloc(256);
    unsigned int* xb = (unsigned int*)d_out;                       // bf16 ping buffer in d_out

    hipMemsetAsync(cnt, 0, (size_t)n * 4, stream);
    hipMemsetAsync(ovf_cnt, 0, 4, stream);

    int enw = 8192; if (2 * E < enw) enw = 2 * E;
    int xnh = 16384; if (n * DF < xnh) xnh = n * DF;
    detect_flags_kernel<<<1, 256, 0, stream>>>((const unsigned int*)eidx, enw,
                                               (const unsigned short*)x, xnh, flagI, flagD);

    int e8 = (E + 7) / 8;                       // threads (8 edges each)
    int g1 = (e8 + 255) / 256;                  // count/slot blocks
    int nw2 = n * 32;                           // uint2 count for cast_x
    int g2 = (nw2 + 255) / 256;                 // cast_x blocks
    int g3 = 64;                                // cast_wb blocks

    // fused prep: count+slot (atomic-latency) overlapped with cast_x/cast_wb (streaming)
    prep_kernel<<<g1 + g2 + g3, 256, 0, stream>>>(
        eidx, flagI, flagD, E, n, cnt, csrF, ovf, ovf_cnt,
        x, (uint2*)xb, nw2, W, b, Wb, bias_f, g1, g2);

    // hops ping-pong: xb(d_out) -> hb(ws) -> xb -> hb ; fixup applies overflow edges
    int hb_grid = (n + 3) / 4;
    hop_kernel<<<hb_grid, 256, 0, stream>>>((const uint4*)xb, (uint4*)hb, csrF, cnt, n);
    fixup_kernel<<<1, 64, 0, stream>>>((const unsigned int*)xb, hb, ovf, ovf_cnt, cnt);
    hop_kernel<<<hb_grid, 256, 0, stream>>>((const uint4*)hb, (uint4*)xb, csrF, cnt, n);
    fixup_kernel<<<1, 64, 0, stream>>>((const unsigned int*)hb, xb, ovf, ovf_cnt, cnt);
    hop_kernel<<<hb_grid, 256, 0, stream>>>((const uint4*)xb, (uint4*)hb, csrF, cnt, n);
    fixup_kernel<<<1, 64, 0, stream>>>((const unsigned int*)xb, hb, ovf, ovf_cnt, cnt);

    // linear: reads hb (ws), writes full d_out (xb region is dead)
    int nstrips = (n + 15) / 16;
    int lgrid = 512; if ((nstrips + 3) / 4 < lgrid) lgrid = (nstrips + 3) / 4;
    linear_mfma_kernel<<<lgrid, 256, 0, stream>>>(
        (const unsigned short*)hb, Wb, bias_f, d_out, flagD, n);
}

// Round 17
// 311.780 us; speedup vs baseline: 1.0248x; 1.0248x over previous
//
#include <hip/hip_runtime.h>
#include <hip/hip_bf16.h>

#define DF 128
#define CAP 32        // fixed CSR slots per node; Poisson(8) max deg ~24 over 100K nodes
#define OVF_CAP 65536 // overflow edge list capacity (expected 0 used)

// flagI: 1 = edge_index stored as int64, 0 = int32
// flagD: 1 = x/W/b/out are bf16, 0 = fp32

typedef __attribute__((ext_vector_type(8))) short shortx8;   // MFMA A/B frag (8 bf16)
typedef __attribute__((ext_vector_type(4))) float floatx4;   // MFMA C/D frag

__device__ __forceinline__ unsigned short f32_to_bf16_rne(float f) {
    unsigned int u = __float_as_uint(f);
    unsigned int r = (u >> 16) & 1u;
    u += 0x7FFFu + r;
    return (unsigned short)(u >> 16);
}
__device__ __forceinline__ float bf16_lo(unsigned int w) { return __uint_as_float(w << 16); }
__device__ __forceinline__ float bf16_hi(unsigned int w) { return __uint_as_float(w & 0xffff0000u); }
__device__ __forceinline__ unsigned int pack_bf16(float x, float y) {
    return ((unsigned int)f32_to_bf16_rne(y) << 16) | (unsigned int)f32_to_bf16_rne(x);
}

// ---------------- INIT: flag detection (block 0) + zero cnt/ovf_cnt (other blocks) ----
// Replaces 2 hipMemsetAsync + detect_flags launch: 3 serial dispatches -> 1.
__global__ __launch_bounds__(256) void init_kernel(const unsigned int* __restrict__ ew, int enwords,
                                                   const unsigned short* __restrict__ xh, int xnh,
                                                   int* __restrict__ flagI, int* __restrict__ flagD,
                                                   int* __restrict__ cnt, int n,
                                                   int* __restrict__ ovf_cnt) {
    int bid = (int)blockIdx.x;
    if (bid == 0) {
        __shared__ int eodd_nz;
        __shared__ int xbig;
        if (threadIdx.x == 0) { eodd_nz = 0; xbig = 0; }
        __syncthreads();
        int f1 = 0;
        for (int i = 1 + 2 * (int)threadIdx.x; i < enwords; i += 2 * (int)blockDim.x)
            if (ew[i] != 0u) f1 = 1;
        int c = 0;
        for (int i = 2 * (int)threadIdx.x; i < xnh; i += 2 * (int)blockDim.x) {
            unsigned int e = ((unsigned int)xh[i] >> 7) & 0xFFu;
            if (e >= 0xC0u) c++;   // |v| >= 2^65 viewed as bf16 -> impossible for real data
        }
        if (f1) eodd_nz = 1;
        if (c) atomicAdd(&xbig, c);
        __syncthreads();
        if (threadIdx.x == 0) {
            *flagI = (eodd_nz == 0) ? 1 : 0;
            *flagD = (xbig > 8) ? 0 : 1;
            *ovf_cnt = 0;
        }
    } else {
        // zero cnt: blocks 1..; int4 stores over the 4B-counter array
        int n4 = n >> 2;                       // full int4 chunks
        int i = (bid - 1) * 256 + (int)threadIdx.x;
        if (i < n4) ((int4*)cnt)[i] = make_int4(0, 0, 0, 0);
        // scalar tail (n not divisible by 4)
        int tail0 = n4 << 2;
        int t = tail0 + i;
        if (i < 4 && t < n) cnt[t] = 0;
    }
}

// ---------------- PREP: count + direct fixed-stride CSR slot write + casts (fused) ----
// Round-14 verdict: 8 edges/thread (2x MLP) + nt stores changed NOTHING (66->62-66us,
// WRITE 72.7->73.8MB) -> prep is at a fabric atomic/scattered-write THROUGHPUT wall,
// not latency. Inner loop frozen as measured; no further attacks here.
__global__ __launch_bounds__(256) void prep_kernel(
        const int* __restrict__ eidx, const int* __restrict__ flagI,
        const int* __restrict__ flagD, int E, int n,
        int* __restrict__ cnt, int* __restrict__ csrF,
        int2* __restrict__ ovf, int* __restrict__ ovf_cnt,
        const void* __restrict__ x, uint2* __restrict__ xb, int nw2,
        const void* __restrict__ W, const void* __restrict__ b,
        unsigned short* __restrict__ Wb, float* __restrict__ bias_f,
        int g1, int g2) {
    int bid = (int)blockIdx.x;
    if (bid < g1) {
        // ---- count + slot write: 8 edges/thread, 8 independent atomics in flight ----
        int t = bid * 256 + (int)threadIdx.x;
        int base = t * 8;
        if (base >= E) return;
        int isI64 = *flagI;
        const long long* p64 = (const long long*)eidx;
        int s[8], d[8];
#pragma unroll
        for (int j = 0; j < 8; ++j) {
            int e = base + j;
            if (e < E) {
                if (isI64) { s[j] = (int)p64[e]; d[j] = (int)p64[(long long)E + e]; }
                else       { s[j] = eidx[e];     d[j] = eidx[E + e]; }
            } else { s[j] = -1; d[j] = -1; }
        }
        int r[8];
#pragma unroll
        for (int j = 0; j < 8; ++j) {
            bool ok = ((unsigned)d[j] < (unsigned)n) && ((unsigned)s[j] < (unsigned)n);
            r[j] = ok ? atomicAdd(&cnt[d[j]], 1) : -1;
        }
#pragma unroll
        for (int j = 0; j < 8; ++j) {
            if (r[j] < 0) continue;
            if (r[j] < CAP) {
                __builtin_nontemporal_store(s[j], &csrF[d[j] * CAP + r[j]]);
            } else {
                int p = atomicAdd(ovf_cnt, 1);
                if (p < OVF_CAP) ovf[p] = make_int2(s[j], d[j]);
            }
        }
    } else if (bid < g1 + g2) {
        // ---- cast_x: x -> packed bf16 rows (or copy if already bf16) ----
        int i = (bid - g1) * 256 + (int)threadIdx.x;
        if (i >= nw2) return;
        if (*flagD) {
            xb[i] = ((const uint2*)x)[i];
        } else {
            float4 v = ((const float4*)x)[i];
            uint2 o;
            o.x = pack_bf16(v.x, v.y);
            o.y = pack_bf16(v.z, v.w);
            xb[i] = o;
        }
    } else {
        // ---- cast_wb: W -> bf16, b -> fp32 ----
        int i = (bid - g1 - g2) * 256 + (int)threadIdx.x;
        int bf = *flagD;
        if (i < 128 * 128)
            Wb[i] = bf ? ((const unsigned short*)W)[i] : f32_to_bf16_rne(((const float*)W)[i]);
        if (i < 128)
            bias_f[i] = bf ? bf16_lo((unsigned int)((const unsigned short*)b)[i]) : ((const float*)b)[i];
    }
}

// ---------------- hop: one wave per node, quarter-wave uint4 gathers, 2x-MLP ----------------
// Fixed-stride CSR: beg = gw*CAP, length cnt[gw] (<=CAP). Overflow edges (cnt>CAP,
// expected ZERO for real data) are handled IN-WAVE via a scan of the tiny ovf list —
// replaces the 3 separate fixup kernel launches. Common-path cost: one wave-uniform
// compare (cv>CAP), never taken.
// out[i] = di*(di*self + sum_s w_s*h[s]),  di = rsqrt(cnt[i]+1)
__global__ __launch_bounds__(256) void hop_kernel(const uint4* __restrict__ hin,
                                                  uint4* __restrict__ hout,
                                                  const int* __restrict__ csrF,
                                                  const int* __restrict__ cnt,
                                                  const int2* __restrict__ ovf,
                                                  const int* __restrict__ ovf_cnt, int n) {
    int gw = (int)((blockIdx.x * 256 + threadIdx.x) >> 6);
    int lane = (int)(threadIdx.x & 63);
    if (gw >= n) return;
    int e = lane >> 4, c = lane & 15;
    int cv = cnt[gw];
    float di = rsqrtf((float)(cv + 1));
    int beg = gw * CAP;
    int len = cv < CAP ? cv : CAP;
    int end = beg + len;
    uint4 sv = hin[(size_t)gw * 16 + c];     // self row (broadcast across quarters)
    float a0 = 0.f, a1 = 0.f, a2 = 0.f, a3 = 0.f, a4 = 0.f, a5 = 0.f, a6 = 0.f, a7 = 0.f;
    for (int j = beg + e; j < end; j += 8) {
        int s0 = csrF[j];
        bool has1 = (j + 4) < end;
        int s1 = has1 ? csrF[j + 4] : s0;
        uint4 v0 = hin[(size_t)s0 * 16 + c];          // two independent gathers
        uint4 v1 = hin[(size_t)s1 * 16 + c];          // in flight concurrently
        float w0 = rsqrtf((float)(cnt[s0] + 1));
        float w1 = has1 ? rsqrtf((float)(cnt[s1] + 1)) : 0.f;
        a0 += w0 * bf16_lo(v0.x); a1 += w0 * bf16_hi(v0.x);
        a2 += w0 * bf16_lo(v0.y); a3 += w0 * bf16_hi(v0.y);
        a4 += w0 * bf16_lo(v0.z); a5 += w0 * bf16_hi(v0.z);
        a6 += w0 * bf16_lo(v0.w); a7 += w0 * bf16_hi(v0.w);
        a0 += w1 * bf16_lo(v1.x); a1 += w1 * bf16_hi(v1.x);
        a2 += w1 * bf16_lo(v1.y); a3 += w1 * bf16_hi(v1.y);
        a4 += w1 * bf16_lo(v1.z); a5 += w1 * bf16_hi(v1.z);
        a6 += w1 * bf16_lo(v1.w); a7 += w1 * bf16_hi(v1.w);
    }
    // overflow tail (never taken for real data): quarter 0 scans the ovf list
    if (cv > CAP && e == 0) {
        int m = *ovf_cnt; if (m > OVF_CAP) m = OVF_CAP;
        for (int i = 0; i < m; ++i) {
            int2 ov = ovf[i];
            if (ov.y != gw) continue;
            float w = rsqrtf((float)(cnt[ov.x] + 1));
            uint4 v = hin[(size_t)ov.x * 16 + c];
            a0 += w * bf16_lo(v.x); a1 += w * bf16_hi(v.x);
            a2 += w * bf16_lo(v.y); a3 += w * bf16_hi(v.y);
            a4 += w * bf16_lo(v.z); a5 += w * bf16_hi(v.z);
            a6 += w * bf16_lo(v.w); a7 += w * bf16_hi(v.w);
        }
    }
    // reduce the 4 quarter-partials for each column set
    a0 += __shfl_xor(a0, 16); a0 += __shfl_xor(a0, 32);
    a1 += __shfl_xor(a1, 16); a1 += __shfl_xor(a1, 32);
    a2 += __shfl_xor(a2, 16); a2 += __shfl_xor(a2, 32);
    a3 += __shfl_xor(a3, 16); a3 += __shfl_xor(a3, 32);
    a4 += __shfl_xor(a4, 16); a4 += __shfl_xor(a4, 32);
    a5 += __shfl_xor(a5, 16); a5 += __shfl_xor(a5, 32);
    a6 += __shfl_xor(a6, 16); a6 += __shfl_xor(a6, 32);
    a7 += __shfl_xor(a7, 16); a7 += __shfl_xor(a7, 32);
    // add self term and final scale
    a0 = di * (a0 + di * bf16_lo(sv.x)); a1 = di * (a1 + di * bf16_hi(sv.x));
    a2 = di * (a2 + di * bf16_lo(sv.y)); a3 = di * (a3 + di * bf16_hi(sv.y));
    a4 = di * (a4 + di * bf16_lo(sv.z)); a5 = di * (a5 + di * bf16_hi(sv.z));
    a6 = di * (a6 + di * bf16_lo(sv.w)); a7 = di * (a7 + di * bf16_hi(sv.w));
    if (e == 0) {
        uint4 o;
        o.x = pack_bf16(a0, a1);
        o.y = pack_bf16(a2, a3);
        o.z = pack_bf16(a4, a5);
        o.w = pack_bf16(a6, a7);
        hout[(size_t)gw * 16 + c] = o;
    }
}

// ---------------- MFMA linear: out = h @ Wb^T + bias (h,Wb bf16; out per flagD) ----------------
__global__ __launch_bounds__(256, 2) void linear_mfma_kernel(
        const unsigned short* __restrict__ h, const unsigned short* __restrict__ Wb,
        const float* __restrict__ bias_f, void* __restrict__ out,
        const int* __restrict__ flagD, int n) {
    int bf = *flagD;
    int wave = (int)(threadIdx.x >> 6);
    int lane = (int)(threadIdx.x & 63);
    int q = lane >> 4, m16 = lane & 15;

    shortx8 bfrag[8][4];
    float bias[8];
#pragma unroll
    for (int nt = 0; nt < 8; ++nt) {
        int wr = nt * 16 + m16;               // W row = output feature o
#pragma unroll
        for (int t = 0; t < 4; ++t)
            bfrag[nt][t] = *(const shortx8*)&Wb[wr * 128 + t * 32 + q * 8];
        bias[nt] = bias_f[wr];
    }

    int nstrips = (n + 15) / 16;
    int wid = (int)blockIdx.x * 4 + wave;
    int nw = (int)gridDim.x * 4;
    for (int s = wid; s < nstrips; s += nw) {
        int row0 = s * 16;
        int arow = row0 + m16;
        if (arow >= n) arow = n - 1;          // clamp (dup rows; stores guarded)
        shortx8 afrag[4];
#pragma unroll
        for (int t = 0; t < 4; ++t)
            afrag[t] = *(const shortx8*)&h[(size_t)arow * 128 + t * 32 + q * 8];

        floatx4 acc[8];
#pragma unroll
        for (int nt = 0; nt < 8; ++nt) acc[nt] = (floatx4){0.f, 0.f, 0.f, 0.f};
#pragma unroll
        for (int t = 0; t < 4; ++t)
#pragma unroll
            for (int nt = 0; nt < 8; ++nt)
                acc[nt] = __builtin_amdgcn_mfma_f32_16x16x32_bf16(afrag[t], bfrag[nt][t], acc[nt], 0, 0, 0);

#pragma unroll
        for (int nt = 0; nt < 8; ++nt)
#pragma unroll
            for (int r = 0; r < 4; ++r) {
                int row = row0 + q * 4 + r;
                if (row < n) {
                    float v = acc[nt][r] + bias[nt];
                    size_t oi = (size_t)row * 128 + nt * 16 + m16;
                    if (bf) ((unsigned short*)out)[oi] = f32_to_bf16_rne(v);
                    else    ((float*)out)[oi] = v;
                }
            }
    }
}

extern "C" void kernel_launch(void* const* d_in, const int* in_sizes, int n_in,
                              void* d_out, int out_size, void* d_ws, size_t ws_size,
                              hipStream_t stream) {
    const void* x = d_in[0];
    const int* eidx = (const int*)d_in[1];
    const void* W = d_in[2];
    const void* b = d_in[3];

    int n = in_sizes[0] / DF;   // 100000
    int E = in_sizes[1] / 2;    // 800000

    // workspace carve-up (~40 MB; d_out hosts the second bf16 ping buffer,
    // safe because out_size*2B >= 25.6MB even for bf16 output)
    char* ws = (char*)d_ws;
    size_t off = 0;
    auto alloc = [&](size_t bytes) -> void* {
        void* p = ws + off;
        off = (off + bytes + 255) & ~(size_t)255;
        return p;
    };
    unsigned int* hb = (unsigned int*)alloc((size_t)n * 64 * 4);   // bf16 rows, 25.6MB
    int*   cnt       = (int*)alloc((size_t)n * 4);
    int*   flagI     = (int*)alloc(256);
    int*   flagD     = (int*)alloc(256);
    unsigned short* Wb = (unsigned short*)alloc(128 * 128 * 2);    // bf16 W
    float* bias_f    = (float*)alloc(128 * 4);
    int*   csrF      = (int*)alloc((size_t)n * CAP * 4);           // fixed-stride CSR, 12.8MB
    int2*  ovf       = (int2*)alloc((size_t)OVF_CAP * 8);          // overflow edges, 512KB
    int*   ovf_cnt   = (int*)alloc(256);
    unsigned int* xb = (unsigned int*)d_out;                       // bf16 ping buffer in d_out

    int enw = 8192; if (2 * E < enw) enw = 2 * E;
    int xnh = 16384; if (n * DF < xnh) xnh = n * DF;

    // init: block 0 = flag detection; blocks 1.. zero cnt + ovf_cnt (replaces 2 memsets + detect)
    int nzb = ((n >> 2) + 255) / 256;
    init_kernel<<<1 + nzb, 256, 0, stream>>>((const unsigned int*)eidx, enw,
                                             (const unsigned short*)x, xnh,
                                             flagI, flagD, cnt, n, ovf_cnt);

    int e8 = (E + 7) / 8;                       // threads (8 edges each)
    int g1 = (e8 + 255) / 256;                  // count/slot blocks
    int nw2 = n * 32;                           // uint2 count for cast_x
    int g2 = (nw2 + 255) / 256;                 // cast_x blocks
    int g3 = 64;                                // cast_wb blocks

    // fused prep: count+slot (atomic wall) overlapped with cast_x/cast_wb (streaming)
    prep_kernel<<<g1 + g2 + g3, 256, 0, stream>>>(
        eidx, flagI, flagD, E, n, cnt, csrF, ovf, ovf_cnt,
        x, (uint2*)xb, nw2, W, b, Wb, bias_f, g1, g2);

    // hops ping-pong: xb(d_out) -> hb(ws) -> xb -> hb  (overflow handled in-wave)
    int hb_grid = (n + 3) / 4;
    hop_kernel<<<hb_grid, 256, 0, stream>>>((const uint4*)xb, (uint4*)hb, csrF, cnt, ovf, ovf_cnt, n);
    hop_kernel<<<hb_grid, 256, 0, stream>>>((const uint4*)hb, (uint4*)xb, csrF, cnt, ovf, ovf_cnt, n);
    hop_kernel<<<hb_grid, 256, 0, stream>>>((const uint4*)xb, (uint4*)hb, csrF, cnt, ovf, ovf_cnt, n);

    // linear: reads hb (ws), writes full d_out (xb region is dead)
    int nstrips = (n + 15) / 16;
    int lgrid = 512; if ((nstrips + 3) / 4 < lgrid) lgrid = (nstrips + 3) / 4;
    linear_mfma_kernel<<<lgrid, 256, 0, stream>>>(
        (const unsigned short*)hb, Wb, bias_f, d_out, flagD, n);
}